// Round 2
// baseline (637.873 us; speedup 1.0000x reference)
//
#include <hip/hip_runtime.h>
#include <hip/hip_bf16.h>
#include <cstdint>

#define TPB 256

constexpr int B = 8, C = 684, H = 64, W = 256;
constexpr int HID = 256, A = 512, K = 11;
constexpr int HW = H * W;      // 16384
constexpr int KK = K * K;      // 121
constexpr int FW_LD = 128;     // padded tap stride
constexpr int SM_CHUNKS = 16;  // softmax stage-1 chunks per batch

__device__ __forceinline__ float fast_tanh(float x) {
    // tanh(x) = 1 - 2/(e^{2x}+1); saturates correctly at +/-inf
    float e = __expf(2.f * x);
    return 1.f - 2.f * __builtin_amdgcn_rcpf(e + 1.f);
}

// query[b,a] = hidden[b,:] @ W_h[:,a] + b_h[a]
__global__ void query_kernel(const float* __restrict__ hidden,
                             const float* __restrict__ W_h,
                             const float* __restrict__ b_h,
                             float* __restrict__ query) {
    int idx = blockIdx.x * TPB + threadIdx.x;   // B*A = 4096
    int b = idx >> 9, a = idx & (A - 1);
    float q = b_h[a];
    const float* hb = hidden + b * HID;
    for (int k = 0; k < HID; ++k)
        q = fmaf(hb[k], W_h[k * A + a], q);
    query[idx] = q;
}

// fwT[a][t] = sum_c conv_w[c,0,t] * W_att[c,a]   (t in [0,121), padded to 128 with 0)
__global__ void fw_kernel(const float* __restrict__ conv_w,
                          const float* __restrict__ W_att,
                          float* __restrict__ fwT) {
    int idx = blockIdx.x * TPB + threadIdx.x;   // A*FW_LD = 65536
    int t = idx >> 9, a = idx & (A - 1);
    float v = 0.f;
    if (t < KK) {
        for (int ch = 0; ch < 512; ++ch)
            v = fmaf(conv_w[ch * KK + t], W_att[ch * A + a], v);
    }
    fwT[a * FW_LD + t] = v;
}

// energy[b,h,w] = sum_a tanh(query[b,a] + cov[b,h,w,a] + trans[b,a,h,w]) * W_alpha[a] + b_alpha
__global__ __launch_bounds__(TPB, 2) void energy_kernel(
    const float* __restrict__ alpha_sum,
    const float* __restrict__ trans,
    const float* __restrict__ query,
    const float* __restrict__ fwT,
    const float* __restrict__ W_alpha,
    const float* __restrict__ b_alpha,
    float* __restrict__ energy) {
    const int h = blockIdx.x;
    const int b = blockIdx.y;
    const int w = threadIdx.x;

    __shared__ float nb[K][272];
    const float* as_b = alpha_sum + b * HW;
    for (int idx = threadIdx.x; idx < K * 266; idx += TPB) {
        int r = idx / 266, j = idx % 266;
        int gh = h + r - 5, gw = j - 5;
        float v = 0.f;
        if (gh >= 0 && gh < H && gw >= 0 && gw < W)
            v = as_b[gh * W + gw];
        nb[r][j] = v;
    }
    __syncthreads();

    // per-pixel 11x11 neighborhood pinned in VGPRs (asm blocks rematerialization)
    float nbr[KK];
#pragma unroll
    for (int r = 0; r < K; ++r)
#pragma unroll
        for (int c = 0; c < K; ++c) {
            float v = nb[r][w + c];
            asm volatile("" : "+v"(v));
            nbr[r * K + c] = v;
        }

    const float* qb = query + b * A;
    const float* tb = trans + (size_t)b * A * HW + h * W + w;
    float eacc = 0.f;
    for (int a0 = 0; a0 < A; a0 += 4) {
        const float* f0 = fwT + (a0 + 0) * FW_LD;  // uniform -> s_load streams
        const float* f1 = fwT + (a0 + 1) * FW_LD;
        const float* f2 = fwT + (a0 + 2) * FW_LD;
        const float* f3 = fwT + (a0 + 3) * FW_LD;
        float t0 = tb[(size_t)(a0 + 0) * HW];      // issued early, used late
        float t1 = tb[(size_t)(a0 + 1) * HW];
        float t2 = tb[(size_t)(a0 + 2) * HW];
        float t3 = tb[(size_t)(a0 + 3) * HW];
        float c0a = 0.f, c0b = 0.f, c1a = 0.f, c1b = 0.f;
        float c2a = 0.f, c2b = 0.f, c3a = 0.f, c3b = 0.f;
#pragma unroll
        for (int t = 0; t < KK - 1; t += 2) {
            c0a = fmaf(nbr[t], f0[t], c0a);
            c0b = fmaf(nbr[t + 1], f0[t + 1], c0b);
            c1a = fmaf(nbr[t], f1[t], c1a);
            c1b = fmaf(nbr[t + 1], f1[t + 1], c1b);
            c2a = fmaf(nbr[t], f2[t], c2a);
            c2b = fmaf(nbr[t + 1], f2[t + 1], c2b);
            c3a = fmaf(nbr[t], f3[t], c3a);
            c3b = fmaf(nbr[t + 1], f3[t + 1], c3b);
        }
        c0a = fmaf(nbr[KK - 1], f0[KK - 1], c0a);
        c1a = fmaf(nbr[KK - 1], f1[KK - 1], c1a);
        c2a = fmaf(nbr[KK - 1], f2[KK - 1], c2a);
        c3a = fmaf(nbr[KK - 1], f3[KK - 1], c3a);
        float x0 = qb[a0 + 0] + (c0a + c0b) + t0;
        float x1 = qb[a0 + 1] + (c1a + c1b) + t1;
        float x2 = qb[a0 + 2] + (c2a + c2b) + t2;
        float x3 = qb[a0 + 3] + (c3a + c3b) + t3;
        eacc = fmaf(fast_tanh(x0), W_alpha[a0 + 0], eacc);
        eacc = fmaf(fast_tanh(x1), W_alpha[a0 + 1], eacc);
        eacc = fmaf(fast_tanh(x2), W_alpha[a0 + 2], eacc);
        eacc = fmaf(fast_tanh(x3), W_alpha[a0 + 3], eacc);
    }
    energy[(b * H + h) * W + w] = eacc + b_alpha[0];
}

// softmax stage 1: per-(b,chunk) partial max + sum(exp(e-m)*mask)
__global__ void softmax_part_kernel(const float* __restrict__ energy,
                                    const float* __restrict__ mask,
                                    float* __restrict__ pm,
                                    float* __restrict__ ps) {
    const int chunk = blockIdx.x, b = blockIdx.y;
    const int base = (b * HW + chunk * (HW / SM_CHUNKS)) / 4;
    const float4* e4 = (const float4*)energy + base;
    const float4* m4 = (const float4*)mask + base;
    float4 ev = e4[threadIdx.x];
    float4 mv = m4[threadIdx.x];
    float m = fmaxf(fmaxf(ev.x, ev.y), fmaxf(ev.z, ev.w));
    float s = __expf(ev.x - m) * mv.x + __expf(ev.y - m) * mv.y +
              __expf(ev.z - m) * mv.z + __expf(ev.w - m) * mv.w;
    __shared__ float sm[TPB], ss[TPB];
    sm[threadIdx.x] = m; ss[threadIdx.x] = s;
    __syncthreads();
    for (int str = TPB / 2; str > 0; str >>= 1) {
        if (threadIdx.x < str) {
            float m2 = sm[threadIdx.x + str], s2 = ss[threadIdx.x + str];
            float m1 = sm[threadIdx.x], s1 = ss[threadIdx.x];
            float nm = fmaxf(m1, m2);
            sm[threadIdx.x] = nm;
            ss[threadIdx.x] = s1 * __expf(m1 - nm) + s2 * __expf(m2 - nm);
        }
        __syncthreads();
    }
    if (threadIdx.x == 0) {
        pm[b * SM_CHUNKS + chunk] = sm[0];
        ps[b * SM_CHUNKS + chunk] = ss[0];
    }
}

// softmax stage 2: combine partials -> maxv[b], invd[b]
__global__ void softmax_comb_kernel(const float* __restrict__ pm,
                                    const float* __restrict__ ps,
                                    float* __restrict__ maxv,
                                    float* __restrict__ invd) {
    const int b = blockIdx.x;
    int lane = threadIdx.x;
    float m = (lane < SM_CHUNKS) ? pm[b * SM_CHUNKS + lane] : -1e30f;
    float s = (lane < SM_CHUNKS) ? ps[b * SM_CHUNKS + lane] : 0.f;
    for (int off = SM_CHUNKS / 2; off > 0; off >>= 1) {
        float m2 = __shfl_xor(m, off, 64);
        float s2 = __shfl_xor(s, off, 64);
        float nm = fmaxf(m, m2);
        s = s * __expf(m - nm) + s2 * __expf(m2 - nm);
        m = nm;
    }
    if (lane == 0) {
        maxv[b] = m;
        invd[b] = 1.f / (s + 1e-10f);
    }
}

// alpha, new_alpha_sum, masked alpha
__global__ void alpha_kernel(const float* __restrict__ energy,
                             const float* __restrict__ mask,
                             const float* __restrict__ alpha_sum,
                             const float* __restrict__ maxv,
                             const float* __restrict__ invd,
                             float* __restrict__ out_alpha,
                             float* __restrict__ out_nas,
                             float* __restrict__ am) {
    int i = blockIdx.x * TPB + threadIdx.x;   // B*HW
    int b = i >> 14;
    float al = __expf(energy[i] - maxv[b]) * mask[i] * invd[b];
    out_alpha[i] = al;
    out_nas[i] = al + alpha_sum[i];
    am[i] = (al > 0.02f) ? al : 0.f;
}

// context[b,c] = sum_hw am[b,hw] * feat[b,c,hw]
__global__ void context_kernel(const float* __restrict__ feat,
                               const float* __restrict__ am,
                               float* __restrict__ out_ctx) {
    const int c = blockIdx.x, b = blockIdx.y;
    const float4* f4 = (const float4*)(feat + ((size_t)b * C + c) * HW);
    const float4* a4 = (const float4*)(am + b * HW);
    float s = 0.f;
    for (int i = threadIdx.x; i < HW / 4; i += TPB) {
        float4 fv = f4[i];
        float4 av = a4[i];
        s += fv.x * av.x + fv.y * av.y + fv.z * av.z + fv.w * av.w;
    }
    for (int off = 32; off > 0; off >>= 1) s += __shfl_down(s, off, 64);
    __shared__ float ls[TPB / 64];
    int lane = threadIdx.x & 63, wid = threadIdx.x >> 6;
    if (lane == 0) ls[wid] = s;
    __syncthreads();
    if (threadIdx.x == 0) {
        float t = 0.f;
        for (int i = 0; i < TPB / 64; ++i) t += ls[i];
        out_ctx[b * C + c] = t;
    }
}

extern "C" void kernel_launch(void* const* d_in, const int* in_sizes, int n_in,
                              void* d_out, int out_size, void* d_ws, size_t ws_size,
                              hipStream_t stream) {
    const float* cnn_features = (const float*)d_in[0];
    const float* trans        = (const float*)d_in[1];
    const float* hidden       = (const float*)d_in[2];
    const float* alpha_sum    = (const float*)d_in[3];
    const float* image_mask   = (const float*)d_in[4];
    const float* W_h          = (const float*)d_in[5];
    const float* b_h          = (const float*)d_in[6];
    const float* conv_w       = (const float*)d_in[7];
    const float* W_att        = (const float*)d_in[8];
    const float* W_alpha      = (const float*)d_in[9];
    const float* b_alpha      = (const float*)d_in[10];

    float* out       = (float*)d_out;
    float* out_ctx   = out;               // B*C
    float* out_alpha = out + B * C;       // B*HW
    float* out_nas   = out_alpha + B * HW;

    float* ws     = (float*)d_ws;
    float* query  = ws;                   // 4096
    float* fwT    = query + B * A;        // 65536
    float* energy = fwT + A * FW_LD;      // 131072
    float* maxv   = energy + B * HW;      // 8
    float* invd   = maxv + 8;             // 8
    float* am     = invd + 8;             // 131072
    float* pm     = am + B * HW;          // B*SM_CHUNKS
    float* ps     = pm + B * SM_CHUNKS;   // B*SM_CHUNKS

    hipLaunchKernelGGL(query_kernel, dim3((B * A) / TPB), dim3(TPB), 0, stream,
                       hidden, W_h, b_h, query);
    hipLaunchKernelGGL(fw_kernel, dim3((A * FW_LD) / TPB), dim3(TPB), 0, stream,
                       conv_w, W_att, fwT);
    hipLaunchKernelGGL(energy_kernel, dim3(H, B), dim3(TPB), 0, stream,
                       alpha_sum, trans, query, fwT, W_alpha, b_alpha, energy);
    hipLaunchKernelGGL(softmax_part_kernel, dim3(SM_CHUNKS, B), dim3(TPB), 0, stream,
                       energy, image_mask, pm, ps);
    hipLaunchKernelGGL(softmax_comb_kernel, dim3(B), dim3(64), 0, stream,
                       pm, ps, maxv, invd);
    hipLaunchKernelGGL(alpha_kernel, dim3(B * HW / TPB), dim3(TPB), 0, stream,
                       energy, image_mask, alpha_sum, maxv, invd,
                       out_alpha, out_nas, am);
    hipLaunchKernelGGL(context_kernel, dim3(C, B), dim3(TPB), 0, stream,
                       cnn_features, am, out_ctx);
}

// Round 3
// 211.758 us; speedup vs baseline: 3.0123x; 3.0123x over previous
//
#include <hip/hip_runtime.h>
#include <hip/hip_bf16.h>
#include <cstdint>

#define TPB 256

constexpr int B = 8, C = 684, H = 64, W = 256;
constexpr int HID = 256, A = 512, K = 11;
constexpr int HW = H * W;      // 16384
constexpr int KK = K * K;      // 121
constexpr int KP = 128;        // padded tap count (K-dim for MFMA)
constexpr int SM_CHUNKS = 16;

typedef __attribute__((ext_vector_type(8))) short bf16x8;
typedef __attribute__((ext_vector_type(4))) float f32x4;

__device__ __forceinline__ float fast_tanh(float x) {
    // tanh(x) = 1 - 2/(e^{2x}+1); saturates correctly at +/-inf
    float e = __expf(2.f * x);
    return 1.f - 2.f * __builtin_amdgcn_rcpf(e + 1.f);
}

__device__ __forceinline__ unsigned short f2bf(float f) {
    unsigned u = __float_as_uint(f);
    u += 0x7fffu + ((u >> 16) & 1u);   // RNE
    return (unsigned short)(u >> 16);
}

// query[b,a] = hidden[b,:] @ W_h[:,a] + b_h[a]   (kept f32 — used in epilogue)
__global__ void query_kernel(const float* __restrict__ hidden,
                             const float* __restrict__ W_h,
                             const float* __restrict__ b_h,
                             float* __restrict__ query) {
    int idx = blockIdx.x * TPB + threadIdx.x;   // B*A = 4096
    int b = idx >> 9, a = idx & (A - 1);
    float q = b_h[a];
    const float* hb = hidden + b * HID;
    for (int k = 0; k < HID; ++k)
        q = fmaf(hb[k], W_h[k * A + a], q);
    query[idx] = q;
}

// fwb[a][t] = bf16( sum_c conv_w[c,0,t] * W_att[c,a] ), t in [0,121) pad 128 with 0
__global__ void fw_kernel(const float* __restrict__ conv_w,
                          const float* __restrict__ W_att,
                          unsigned short* __restrict__ fwb) {
    int idx = blockIdx.x * TPB + threadIdx.x;   // A*KP = 65536
    int t = idx >> 9, a = idx & (A - 1);        // t uniform per block
    float v = 0.f;
    if (t < KK) {
        for (int ch = 0; ch < 512; ++ch)
            v = fmaf(conv_w[ch * KK + t], W_att[ch * A + a], v);
    }
    fwb[a * KP + t] = f2bf(v);
}

// Implicit-GEMM energy kernel.
// Block = (b,h): 256 pixels x 512 a. 8 waves, wave owns 64 a.
// MFMA 16x16x32 bf16: A-operand = fw (a x taps), B = im2col patch (taps x pixels).
// C layout (m89-verified): col = lane&15 = pixel, row = (lane>>4)*4+reg = a-offset.
__global__ __launch_bounds__(512, 2) void energy_kernel(
    const float* __restrict__ alpha_sum,
    const float* __restrict__ trans,
    const float* __restrict__ query,
    const unsigned short* __restrict__ fwb,
    const float* __restrict__ W_alpha,
    const float* __restrict__ b_alpha,
    float* __restrict__ energy) {
    const int h = blockIdx.x, b = blockIdx.y;
    const int tid = threadIdx.x;
    const int lane = tid & 63, wid = tid >> 6;
    const int lg = lane >> 4, lr = lane & 15;   // k-group, row-in-16
    const int aw = wid * 64;                    // wave's a-base

    __shared__ float nb[K][272];                // alpha_sum halo rows
    __shared__ unsigned short patch[16 * KP];   // [p][tap] bf16, XOR-swizzled
    __shared__ float part[8][16];

    // stage halo: rows h-5..h+5, cols -5..260
    const float* as_b = alpha_sum + b * HW;
    for (int idx = tid; idx < K * 266; idx += 512) {
        int r = idx / 266, j = idx - r * 266;
        int gh = h + r - 5, gw = j - 5;
        float v = 0.f;
        if (gh >= 0 && gh < H && gw >= 0 && gw < W) v = as_b[gh * W + gw];
        nb[r][j] = v;
    }

    // persistent fw A-frags: fw[aw+s*16+lr][ks*32 + lg*8 .. +7]
    bf16x8 fwf[4][4];
#pragma unroll
    for (int s = 0; s < 4; ++s)
#pragma unroll
        for (int ks = 0; ks < 4; ++ks)
            fwf[s][ks] = *(const bf16x8*)(fwb + (aw + s * 16 + lr) * KP + ks * 32 + lg * 8);

    // per-lane q and W_alpha matching C-frag rows
    float qr[4][4], wr[4][4];
#pragma unroll
    for (int s = 0; s < 4; ++s)
#pragma unroll
        for (int j = 0; j < 4; ++j) {
            int a = aw + s * 16 + lg * 4 + j;
            qr[s][j] = query[b * A + a];
            wr[s][j] = W_alpha[a];
        }

    const float* tb = trans + (size_t)b * A * HW + h * W;
    // prologue: trans for pass 0 (coalesced: 16 consecutive pixels per 16-lane group)
    float tc[4][4];
#pragma unroll
    for (int s = 0; s < 4; ++s)
#pragma unroll
        for (int j = 0; j < 4; ++j)
            tc[s][j] = tb[(size_t)(aw + s * 16 + lg * 4 + j) * HW + lr];

    const float bA = b_alpha[0];
    __syncthreads();

    for (int pass = 0; pass < 16; ++pass) {
        const int p0 = pass * 16;
        // ---- build bf16 im2col patch for pixels p0..p0+15 (4 entries/thread) ----
        {
            const int i0 = tid * 4;
            const int p = i0 >> 7;          // 0..15
            const int tap = i0 & 127;       // multiple of 4
            unsigned short e[4];
#pragma unroll
            for (int j = 0; j < 4; ++j) {
                int t = tap + j;
                float v = 0.f;
                if (t < KK) {
                    int r = t / K, c = t - r * K;
                    v = nb[r][p0 + p + c];
                }
                e[j] = f2bf(v);
            }
            uint2 pk;
            pk.x = (unsigned)e[0] | ((unsigned)e[1] << 16);
            pk.y = (unsigned)e[2] | ((unsigned)e[3] << 16);
            int idx = (p * KP + tap) ^ ((p & 7) << 3);   // ushort units; byte ^= (p&7)<<4
            *(uint2*)&patch[idx] = pk;
        }
        __syncthreads();

        // prefetch next pass's trans (hidden under MFMA+epilogue)
        const int p0n = (pass < 15 ? pass + 1 : pass) * 16;
        float tn[4][4];
#pragma unroll
        for (int s = 0; s < 4; ++s)
#pragma unroll
            for (int j = 0; j < 4; ++j)
                tn[s][j] = tb[(size_t)(aw + s * 16 + lg * 4 + j) * HW + p0n + lr];

        // ---- K-loop: 4 k-steps x 4 a-subtiles ----
        f32x4 acc[4];
#pragma unroll
        for (int s = 0; s < 4; ++s) acc[s] = (f32x4){0.f, 0.f, 0.f, 0.f};
#pragma unroll
        for (int ks = 0; ks < 4; ++ks) {
            int idx = (lr * KP + ks * 32 + lg * 8) ^ ((lr & 7) << 3);
            bf16x8 pf = *(const bf16x8*)&patch[idx];
#pragma unroll
            for (int s = 0; s < 4; ++s)
                acc[s] = __builtin_amdgcn_mfma_f32_16x16x32_bf16(fwf[s][ks], pf, acc[s], 0, 0, 0);
        }

        // ---- fused epilogue: tanh(cov + q + trans) * w_alpha, reduce over a ----
        float es = 0.f;
#pragma unroll
        for (int s = 0; s < 4; ++s)
#pragma unroll
            for (int j = 0; j < 4; ++j) {
                float x = acc[s][j] + qr[s][j] + tc[s][j];
                es = fmaf(fast_tanh(x), wr[s][j], es);
            }
        // lanes {l, l^16, l^32, l^48} share pixel lr -> reduce over a-groups
        es += __shfl_xor(es, 16, 64);
        es += __shfl_xor(es, 32, 64);
        if (lane < 16) part[wid][lane] = es;
        __syncthreads();

        if (tid < 16) {
            float e = part[0][tid];
#pragma unroll
            for (int wv = 1; wv < 8; ++wv) e += part[wv][tid];
            energy[(b * H + h) * W + p0 + tid] = e + bA;
        }
#pragma unroll
        for (int s = 0; s < 4; ++s)
#pragma unroll
            for (int j = 0; j < 4; ++j)
                tc[s][j] = tn[s][j];
    }
}

// softmax stage 1: per-(b,chunk) partial max + sum(exp(e-m)*mask)
__global__ void softmax_part_kernel(const float* __restrict__ energy,
                                    const float* __restrict__ mask,
                                    float* __restrict__ pm,
                                    float* __restrict__ ps) {
    const int chunk = blockIdx.x, b = blockIdx.y;
    const int base = (b * HW + chunk * (HW / SM_CHUNKS)) / 4;
    const float4* e4 = (const float4*)energy + base;
    const float4* m4 = (const float4*)mask + base;
    float4 ev = e4[threadIdx.x];
    float4 mv = m4[threadIdx.x];
    float m = fmaxf(fmaxf(ev.x, ev.y), fmaxf(ev.z, ev.w));
    float s = __expf(ev.x - m) * mv.x + __expf(ev.y - m) * mv.y +
              __expf(ev.z - m) * mv.z + __expf(ev.w - m) * mv.w;
    __shared__ float sm[TPB], ss[TPB];
    sm[threadIdx.x] = m; ss[threadIdx.x] = s;
    __syncthreads();
    for (int str = TPB / 2; str > 0; str >>= 1) {
        if (threadIdx.x < str) {
            float m2 = sm[threadIdx.x + str], s2 = ss[threadIdx.x + str];
            float m1 = sm[threadIdx.x], s1 = ss[threadIdx.x];
            float nm = fmaxf(m1, m2);
            sm[threadIdx.x] = nm;
            ss[threadIdx.x] = s1 * __expf(m1 - nm) + s2 * __expf(m2 - nm);
        }
        __syncthreads();
    }
    if (threadIdx.x == 0) {
        pm[b * SM_CHUNKS + chunk] = sm[0];
        ps[b * SM_CHUNKS + chunk] = ss[0];
    }
}

__global__ void softmax_comb_kernel(const float* __restrict__ pm,
                                    const float* __restrict__ ps,
                                    float* __restrict__ maxv,
                                    float* __restrict__ invd) {
    const int b = blockIdx.x;
    int lane = threadIdx.x;
    float m = (lane < SM_CHUNKS) ? pm[b * SM_CHUNKS + lane] : -1e30f;
    float s = (lane < SM_CHUNKS) ? ps[b * SM_CHUNKS + lane] : 0.f;
    for (int off = SM_CHUNKS / 2; off > 0; off >>= 1) {
        float m2 = __shfl_xor(m, off, 64);
        float s2 = __shfl_xor(s, off, 64);
        float nm = fmaxf(m, m2);
        s = s * __expf(m - nm) + s2 * __expf(m2 - nm);
        m = nm;
    }
    if (lane == 0) {
        maxv[b] = m;
        invd[b] = 1.f / (s + 1e-10f);
    }
}

__global__ void alpha_kernel(const float* __restrict__ energy,
                             const float* __restrict__ mask,
                             const float* __restrict__ alpha_sum,
                             const float* __restrict__ maxv,
                             const float* __restrict__ invd,
                             float* __restrict__ out_alpha,
                             float* __restrict__ out_nas,
                             float* __restrict__ am) {
    int i = blockIdx.x * TPB + threadIdx.x;   // B*HW
    int b = i >> 14;
    float al = __expf(energy[i] - maxv[b]) * mask[i] * invd[b];
    out_alpha[i] = al;
    out_nas[i] = al + alpha_sum[i];
    am[i] = (al > 0.02f) ? al : 0.f;
}

// context[b,c] = sum_hw am[b,hw] * feat[b,c,hw]
__global__ void context_kernel(const float* __restrict__ feat,
                               const float* __restrict__ am,
                               float* __restrict__ out_ctx) {
    const int c = blockIdx.x, b = blockIdx.y;
    const float4* f4 = (const float4*)(feat + ((size_t)b * C + c) * HW);
    const float4* a4 = (const float4*)(am + b * HW);
    float s = 0.f;
    for (int i = threadIdx.x; i < HW / 4; i += TPB) {
        float4 fv = f4[i];
        float4 av = a4[i];
        s += fv.x * av.x + fv.y * av.y + fv.z * av.z + fv.w * av.w;
    }
    for (int off = 32; off > 0; off >>= 1) s += __shfl_down(s, off, 64);
    __shared__ float ls[TPB / 64];
    int lane = threadIdx.x & 63, wid = threadIdx.x >> 6;
    if (lane == 0) ls[wid] = s;
    __syncthreads();
    if (threadIdx.x == 0) {
        float t = 0.f;
        for (int i = 0; i < TPB / 64; ++i) t += ls[i];
        out_ctx[b * C + c] = t;
    }
}

extern "C" void kernel_launch(void* const* d_in, const int* in_sizes, int n_in,
                              void* d_out, int out_size, void* d_ws, size_t ws_size,
                              hipStream_t stream) {
    const float* cnn_features = (const float*)d_in[0];
    const float* trans        = (const float*)d_in[1];
    const float* hidden       = (const float*)d_in[2];
    const float* alpha_sum    = (const float*)d_in[3];
    const float* image_mask   = (const float*)d_in[4];
    const float* W_h          = (const float*)d_in[5];
    const float* b_h          = (const float*)d_in[6];
    const float* conv_w       = (const float*)d_in[7];
    const float* W_att        = (const float*)d_in[8];
    const float* W_alpha      = (const float*)d_in[9];
    const float* b_alpha      = (const float*)d_in[10];

    float* out       = (float*)d_out;
    float* out_ctx   = out;               // B*C
    float* out_alpha = out + B * C;       // B*HW
    float* out_nas   = out_alpha + B * HW;

    float* ws = (float*)d_ws;
    float*          query  = ws;                          // 4096 f
    unsigned short* fwb    = (unsigned short*)(ws + 4096); // 65536 ushort = 32768 f
    float*          energy = ws + 4096 + 32768;           // 131072 f
    float*          maxv   = energy + B * HW;             // 8
    float*          invd   = maxv + 8;                    // 8
    float*          am     = invd + 8;                    // 131072 f
    float*          pm     = am + B * HW;                 // 128
    float*          ps     = pm + B * SM_CHUNKS;          // 128

    hipLaunchKernelGGL(query_kernel, dim3((B * A) / TPB), dim3(TPB), 0, stream,
                       hidden, W_h, b_h, query);
    hipLaunchKernelGGL(fw_kernel, dim3((A * KP) / TPB), dim3(TPB), 0, stream,
                       conv_w, W_att, fwb);
    hipLaunchKernelGGL(energy_kernel, dim3(H, B), dim3(512), 0, stream,
                       alpha_sum, trans, query, fwb, W_alpha, b_alpha, energy);
    hipLaunchKernelGGL(softmax_part_kernel, dim3(SM_CHUNKS, B), dim3(TPB), 0, stream,
                       energy, image_mask, pm, ps);
    hipLaunchKernelGGL(softmax_comb_kernel, dim3(B), dim3(64), 0, stream,
                       pm, ps, maxv, invd);
    hipLaunchKernelGGL(alpha_kernel, dim3(B * HW / TPB), dim3(TPB), 0, stream,
                       energy, image_mask, alpha_sum, maxv, invd,
                       out_alpha, out_nas, am);
    hipLaunchKernelGGL(context_kernel, dim3(C, B), dim3(TPB), 0, stream,
                       cnn_features, am, out_ctx);
}

// Round 4
// 194.681 us; speedup vs baseline: 3.2765x; 1.0877x over previous
//
#include <hip/hip_runtime.h>
#include <hip/hip_bf16.h>
#include <cstdint>

#define TPB 256

constexpr int B = 8, C = 684, H = 64, W = 256;
constexpr int HID = 256, A = 512, K = 11;
constexpr int HW = H * W;      // 16384
constexpr int KK = K * K;      // 121
constexpr int KP = 128;        // padded tap count (K-dim for MFMA)

typedef __attribute__((ext_vector_type(8))) short bf16x8;
typedef __attribute__((ext_vector_type(4))) float f32x4;

__device__ __forceinline__ float fast_tanh(float x) {
    // tanh(x) = 1 - 2/(e^{2x}+1); saturates correctly at +/-inf
    float e = __expf(2.f * x);
    return 1.f - 2.f * __builtin_amdgcn_rcpf(e + 1.f);
}

__device__ __forceinline__ unsigned short f2bf(float f) {
    unsigned u = __float_as_uint(f);
    u += 0x7fffu + ((u >> 16) & 1u);   // RNE
    return (unsigned short)(u >> 16);
}

// Fused: query[b,a] = hidden[b,:] @ W_h[:,a] + b_h[a]   (blocks 0..15)
//        fwb[a][t]  = bf16(sum_c conv_w[c,0,t] * W_att[c,a])  (blocks 16..271)
__global__ void prep_kernel(const float* __restrict__ hidden,
                            const float* __restrict__ W_h,
                            const float* __restrict__ b_h,
                            const float* __restrict__ conv_w,
                            const float* __restrict__ W_att,
                            float* __restrict__ query,
                            unsigned short* __restrict__ fwb) {
    const int bx = blockIdx.x;
    if (bx < 16) {
        // query: hidden[b,k] is wave-uniform (s_load); W_h row reads coalesced
        int b = bx >> 1;
        int a = ((bx & 1) << 8) + threadIdx.x;
        float q = b_h[a];
        const float* hb = hidden + b * HID;
        for (int k = 0; k < HID; ++k)
            q = fmaf(hb[k], W_h[k * A + a], q);
        query[b * A + a] = q;
    } else {
        int idx = (bx - 16) * TPB + threadIdx.x;   // A*KP = 65536
        int t = idx >> 9, a = idx & (A - 1);       // t uniform per half-block
        float v = 0.f;
        if (t < KK) {
            for (int ch = 0; ch < 512; ++ch)
                v = fmaf(conv_w[ch * KK + t], W_att[ch * A + a], v);
        }
        fwb[a * KP + t] = f2bf(v);
    }
}

// Implicit-GEMM energy kernel + fused per-row softmax partials.
// Block = (b,h): 256 pixels x 512 a. 8 waves, wave owns 64 a.
// MFMA 16x16x32 bf16: A = fw (a x taps), B = im2col patch (taps x pixels).
// C layout (m89-verified): col = lane&15 = pixel, row = (lane>>4)*4+reg = a-offset.
__global__ __launch_bounds__(512, 2) void energy_kernel(
    const float* __restrict__ alpha_sum,
    const float* __restrict__ trans,
    const float* __restrict__ query,
    const unsigned short* __restrict__ fwb,
    const float* __restrict__ W_alpha,
    const float* __restrict__ b_alpha,
    const float* __restrict__ mask,
    float* __restrict__ energy,
    float* __restrict__ pm,
    float* __restrict__ ps) {
    const int h = blockIdx.x, b = blockIdx.y;
    const int tid = threadIdx.x;
    const int lane = tid & 63, wid = tid >> 6;
    const int lg = lane >> 4, lr = lane & 15;   // k-group, row-in-16
    const int aw = wid * 64;                    // wave's a-base

    __shared__ float nb[K][272];                // alpha_sum halo rows
    __shared__ unsigned short patch[16 * KP];   // [p][tap] bf16, XOR-swizzled
    __shared__ float part[8][16];
    __shared__ float erow[256];
    __shared__ float pmw[4], psw[4];

    // stage halo: rows h-5..h+5, cols -5..260
    const float* as_b = alpha_sum + b * HW;
    for (int idx = tid; idx < K * 266; idx += 512) {
        int r = idx / 266, j = idx - r * 266;
        int gh = h + r - 5, gw = j - 5;
        float v = 0.f;
        if (gh >= 0 && gh < H && gw >= 0 && gw < W) v = as_b[gh * W + gw];
        nb[r][j] = v;
    }

    // persistent fw A-frags: fw[aw+s*16+lr][ks*32 + lg*8 .. +7]
    bf16x8 fwf[4][4];
#pragma unroll
    for (int s = 0; s < 4; ++s)
#pragma unroll
        for (int ks = 0; ks < 4; ++ks)
            fwf[s][ks] = *(const bf16x8*)(fwb + (aw + s * 16 + lr) * KP + ks * 32 + lg * 8);

    // per-lane q and W_alpha matching C-frag rows
    float qr[4][4], wr[4][4];
#pragma unroll
    for (int s = 0; s < 4; ++s)
#pragma unroll
        for (int j = 0; j < 4; ++j) {
            int a = aw + s * 16 + lg * 4 + j;
            qr[s][j] = query[b * A + a];
            wr[s][j] = W_alpha[a];
        }

    const float* tb = trans + (size_t)b * A * HW + h * W;
    // prologue: trans for pass 0 (16 consecutive pixels per 16-lane group)
    float tc[4][4];
#pragma unroll
    for (int s = 0; s < 4; ++s)
#pragma unroll
        for (int j = 0; j < 4; ++j)
            tc[s][j] = tb[(size_t)(aw + s * 16 + lg * 4 + j) * HW + lr];

    const float bA = b_alpha[0];
    __syncthreads();

    for (int pass = 0; pass < 16; ++pass) {
        const int p0 = pass * 16;
        // ---- build bf16 im2col patch for pixels p0..p0+15 (4 entries/thread) ----
        {
            const int i0 = tid * 4;
            const int p = i0 >> 7;          // 0..15
            const int tap = i0 & 127;       // multiple of 4
            unsigned short e[4];
#pragma unroll
            for (int j = 0; j < 4; ++j) {
                int t = tap + j;
                float v = 0.f;
                if (t < KK) {
                    int r = t / K, c = t - r * K;
                    v = nb[r][p0 + p + c];
                }
                e[j] = f2bf(v);
            }
            uint2 pk;
            pk.x = (unsigned)e[0] | ((unsigned)e[1] << 16);
            pk.y = (unsigned)e[2] | ((unsigned)e[3] << 16);
            int idx = (p * KP + tap) ^ ((p & 7) << 3);   // ushort units; byte ^= (p&7)<<4
            *(uint2*)&patch[idx] = pk;
        }
        __syncthreads();

        // prefetch next pass's trans (hidden under MFMA+epilogue)
        const int p0n = (pass < 15 ? pass + 1 : pass) * 16;
        float tn[4][4];
#pragma unroll
        for (int s = 0; s < 4; ++s)
#pragma unroll
            for (int j = 0; j < 4; ++j)
                tn[s][j] = tb[(size_t)(aw + s * 16 + lg * 4 + j) * HW + p0n + lr];

        // ---- K-loop: 4 k-steps x 4 a-subtiles ----
        f32x4 acc[4];
#pragma unroll
        for (int s = 0; s < 4; ++s) acc[s] = (f32x4){0.f, 0.f, 0.f, 0.f};
#pragma unroll
        for (int ks = 0; ks < 4; ++ks) {
            int idx = (lr * KP + ks * 32 + lg * 8) ^ ((lr & 7) << 3);
            bf16x8 pf = *(const bf16x8*)&patch[idx];
#pragma unroll
            for (int s = 0; s < 4; ++s)
                acc[s] = __builtin_amdgcn_mfma_f32_16x16x32_bf16(fwf[s][ks], pf, acc[s], 0, 0, 0);
        }

        // ---- fused epilogue: tanh(cov + q + trans) * w_alpha, reduce over a ----
        float es = 0.f;
#pragma unroll
        for (int s = 0; s < 4; ++s)
#pragma unroll
            for (int j = 0; j < 4; ++j) {
                float x = acc[s][j] + qr[s][j] + tc[s][j];
                es = fmaf(fast_tanh(x), wr[s][j], es);
            }
        // lanes {l, l^16, l^32, l^48} share pixel lr -> reduce over a-groups
        es += __shfl_xor(es, 16, 64);
        es += __shfl_xor(es, 32, 64);
        if (lane < 16) part[wid][lane] = es;
        __syncthreads();

        if (tid < 16) {
            float e = part[0][tid];
#pragma unroll
            for (int wv = 1; wv < 8; ++wv) e += part[wv][tid];
            e += bA;
            energy[(b * H + h) * W + p0 + tid] = e;
            erow[p0 + tid] = e;
        }
#pragma unroll
        for (int s = 0; s < 4; ++s)
#pragma unroll
            for (int j = 0; j < 4; ++j)
                tc[s][j] = tn[s][j];
    }

    // ---- fused per-row softmax partial: pm/ps[b*H+h] ----
    __syncthreads();
    if (tid < 256) {
        float v = erow[tid];
        float s = mask[b * HW + h * W + tid];   // exp(v-v)*mk
        float m = v;
#pragma unroll
        for (int off = 1; off < 64; off <<= 1) {
            float m2 = __shfl_xor(m, off, 64);
            float s2 = __shfl_xor(s, off, 64);
            float nm = fmaxf(m, m2);
            s = s * __expf(m - nm) + s2 * __expf(m2 - nm);
            m = nm;
        }
        if ((tid & 63) == 0) { pmw[tid >> 6] = m; psw[tid >> 6] = s; }
    }
    __syncthreads();
    if (tid == 0) {
        float m = pmw[0], s = psw[0];
#pragma unroll
        for (int i = 1; i < 4; ++i) {
            float m2 = pmw[i], s2 = psw[i];
            float nm = fmaxf(m, m2);
            s = s * __expf(m - nm) + s2 * __expf(m2 - nm);
            m = nm;
        }
        pm[b * H + h] = m;
        ps[b * H + h] = s;
    }
}

// alpha + new_alpha_sum + masked alpha; combines the 64 per-row partials inline
__global__ void alpha_kernel(const float* __restrict__ energy,
                             const float* __restrict__ mask,
                             const float* __restrict__ alpha_sum,
                             const float* __restrict__ pm,
                             const float* __restrict__ ps,
                             float* __restrict__ out_alpha,
                             float* __restrict__ out_nas,
                             float* __restrict__ am) {
    const int i = blockIdx.x * TPB + threadIdx.x;   // B*HW
    const int b = i >> 14;                          // uniform per block
    __shared__ float smax, sinv;
    if (threadIdx.x < 64) {
        float m = pm[b * H + threadIdx.x];
        float s = ps[b * H + threadIdx.x];
#pragma unroll
        for (int off = 32; off > 0; off >>= 1) {
            float m2 = __shfl_xor(m, off, 64);
            float s2 = __shfl_xor(s, off, 64);
            float nm = fmaxf(m, m2);
            s = s * __expf(m - nm) + s2 * __expf(m2 - nm);
            m = nm;
        }
        if (threadIdx.x == 0) { smax = m; sinv = 1.f / (s + 1e-10f); }
    }
    __syncthreads();
    float al = __expf(energy[i] - smax) * mask[i] * sinv;
    out_alpha[i] = al;
    out_nas[i] = al + alpha_sum[i];
    am[i] = (al > 0.02f) ? al : 0.f;
}

// context[b,c] = sum_hw am[b,hw] * feat[b,c,hw]
__global__ void context_kernel(const float* __restrict__ feat,
                               const float* __restrict__ am,
                               float* __restrict__ out_ctx) {
    const int c = blockIdx.x, b = blockIdx.y;
    const float4* f4 = (const float4*)(feat + ((size_t)b * C + c) * HW);
    const float4* a4 = (const float4*)(am + b * HW);
    float s = 0.f;
    for (int i = threadIdx.x; i < HW / 4; i += TPB) {
        float4 fv = f4[i];
        float4 av = a4[i];
        s += fv.x * av.x + fv.y * av.y + fv.z * av.z + fv.w * av.w;
    }
    for (int off = 32; off > 0; off >>= 1) s += __shfl_down(s, off, 64);
    __shared__ float ls[TPB / 64];
    int lane = threadIdx.x & 63, wid = threadIdx.x >> 6;
    if (lane == 0) ls[wid] = s;
    __syncthreads();
    if (threadIdx.x == 0) {
        float t = 0.f;
        for (int i = 0; i < TPB / 64; ++i) t += ls[i];
        out_ctx[b * C + c] = t;
    }
}

extern "C" void kernel_launch(void* const* d_in, const int* in_sizes, int n_in,
                              void* d_out, int out_size, void* d_ws, size_t ws_size,
                              hipStream_t stream) {
    const float* cnn_features = (const float*)d_in[0];
    const float* trans        = (const float*)d_in[1];
    const float* hidden       = (const float*)d_in[2];
    const float* alpha_sum    = (const float*)d_in[3];
    const float* image_mask   = (const float*)d_in[4];
    const float* W_h          = (const float*)d_in[5];
    const float* b_h          = (const float*)d_in[6];
    const float* conv_w       = (const float*)d_in[7];
    const float* W_att        = (const float*)d_in[8];
    const float* W_alpha      = (const float*)d_in[9];
    const float* b_alpha      = (const float*)d_in[10];

    float* out       = (float*)d_out;
    float* out_ctx   = out;               // B*C
    float* out_alpha = out + B * C;       // B*HW
    float* out_nas   = out_alpha + B * HW;

    float* ws = (float*)d_ws;
    float*          query  = ws;                           // 4096 f
    unsigned short* fwb    = (unsigned short*)(ws + 4096); // 65536 ushort = 32768 f
    float*          energy = ws + 4096 + 32768;            // 131072 f
    float*          pm     = energy + B * HW;              // 512
    float*          ps     = pm + B * H;                   // 512
    float*          am     = ps + B * H;                   // 131072 f

    hipLaunchKernelGGL(prep_kernel, dim3(16 + (A * KP) / TPB), dim3(TPB), 0, stream,
                       hidden, W_h, b_h, conv_w, W_att, query, fwb);
    hipLaunchKernelGGL(energy_kernel, dim3(H, B), dim3(512), 0, stream,
                       alpha_sum, trans, query, fwb, W_alpha, b_alpha, image_mask,
                       energy, pm, ps);
    hipLaunchKernelGGL(alpha_kernel, dim3(B * HW / TPB), dim3(TPB), 0, stream,
                       energy, image_mask, alpha_sum, pm, ps,
                       out_alpha, out_nas, am);
    hipLaunchKernelGGL(context_kernel, dim3(C, B), dim3(TPB), 0, stream,
                       cnn_features, am, out_ctx);
}